// Round 4
// baseline (6780.675 us; speedup 1.0000x reference)
//
#include <hip/hip_runtime.h>
#include <hip/hip_bf16.h>

#define EPS 1e-5f

// ---------------------------------------------------------------------------
// Layouts:
//   external x : (N=128, C=2, T=256, V=18) row-major (t,v innermost)
//   internal   : (n, c, v, t)  -- t innermost (contiguous, mult of 64)
// Whole network is independent per sample n, so we process N in chunks of NC
// chosen AT RUNTIME from ws_size.  Per-chunk buffers:
//   Us : NC*589824 floats (pre-A-mix GEMM out, max of the 3 blocks)
//   B1 : NC*294912        (block1 out -> reused as block3 out)
//   B2 : NC*294912        (block2 out)
//   XB : NC*9216          (data_bn'd x)
// weights (transposed/prescaled): 856,832 floats at ws base.
// total bytes = 3,427,328 + NC*4,755,456   (NC=32 -> 155.6 MB, NC=1 -> 8.2 MB)
// ---------------------------------------------------------------------------

__global__ __launch_bounds__(256, 4) void k_transpose(
    const float* __restrict__ in, float* __restrict__ out, int rows, int cols) {
  int i = blockIdx.x * 256 + threadIdx.x;
  if (i < rows * cols) {
    int r = i / cols, c = i % cols;
    out[c * rows + r] = in[i];
  }
}

// twT[(c*9+k)*Co + o] = tw[(o*Co+c)*9+k] * s2[o]   (bn2 scale prefolded)
__global__ __launch_bounds__(256, 4) void k_prep_tw(
    const float* __restrict__ tw, const float* __restrict__ bn2g,
    float* __restrict__ twT, int Co) {
  int i = blockIdx.x * 256 + threadIdx.x;
  int total = Co * Co * 9;
  if (i < total) {
    int o = i / (Co * 9);
    int r = i % (Co * 9);
    int c = r / 9, k = r % 9;
    float s2 = bn2g[o] * (1.0f / sqrtf(1.0f + EPS));
    twT[(c * 9 + k) * Co + o] = tw[i] * s2;
  }
}

// beta[o] = s2*tb + b2 + rb
__global__ __launch_bounds__(256, 4) void k_beta(
    const float* __restrict__ bn2g, const float* __restrict__ bn2b,
    const float* __restrict__ tb, const float* __restrict__ rb,
    float* __restrict__ beta, int Co) {
  int o = blockIdx.x * 256 + threadIdx.x;
  if (o < Co)
    beta[o] = bn2g[o] * (1.0f / sqrtf(1.0f + EPS)) * tb[o] + bn2b[o] + rb[o];
}

// block1 front (per n-chunk): data_bn + 1x1 (Ci=2) -> U1 (nc,64,18,256); also xb1
__global__ __launch_bounds__(256, 4) void k_front1(
    const float* __restrict__ x, const float* __restrict__ dbng,
    const float* __restrict__ dbnb, const float* __restrict__ gw,
    float* __restrict__ U1, float* __restrict__ xb1) {
  int n = blockIdx.x, t0 = blockIdx.y * 64;
  __shared__ float xb[2 * 64 * 18];  // [c][tt][v]
  const float rs = 1.0f / sqrtf(1.0f + EPS);
  for (int e = threadIdx.x; e < 2304; e += 256) {
    int c = e / 1152, r = e % 1152;  // r = tt*18+v
    int v = r % 18;
    xb[e] = x[(n * 2 + c) * 4608 + t0 * 18 + r] * (dbng[c * 18 + v] * rs) + dbnb[c * 18 + v];
  }
  __syncthreads();
  for (int e = threadIdx.x; e < 2304; e += 256) {
    int c = e / 1152, r = e % 1152;
    int v = r / 64, tt = r % 64;
    xb1[((size_t)(n * 2 + c) * 18 + v) * 256 + t0 + tt] = xb[c * 1152 + tt * 18 + v];
  }
  for (int e = threadIdx.x; e < 64 * 1152; e += 256) {
    int o = e / 1152, r = e % 1152;
    int v = r / 64, tt = r % 64;
    float g0 = gw[o * 2 + 0], g1 = gw[o * 2 + 1];
    U1[((size_t)(n * 64 + o) * 18 + v) * 256 + t0 + tt] =
        fmaf(g0, xb[tt * 18 + v], g1 * xb[1152 + tt * 18 + v]);
  }
}

// U = gwT^T * X over channels.  X:(nc,CI,18,T)  U:(nc,CO,18,T)  NP = 18*T
template <int CI, int CO>
__global__ __launch_bounds__(256, 4) void k_ugemm(
    const float* __restrict__ X, const float* __restrict__ gwT,
    float* __restrict__ Uo, int NP) {
  const int n = blockIdx.x;
  const int p0 = blockIdx.y * 128;
  const int o0 = blockIdx.z * 64;
  const int og = threadIdx.x & 15, pg = threadIdx.x >> 4;
  const int o = o0 + og * 4, p = p0 + pg * 8;
  __shared__ __align__(16) float xs[32 * 128];
  __shared__ __align__(16) float wsm[32 * 64];
  float acc[4][8] = {};
  const float* Xn = X + (size_t)n * CI * NP;
  for (int c0 = 0; c0 < CI; c0 += 32) {
    __syncthreads();
    for (int e = threadIdx.x; e < 1024; e += 256) {
      int c = e >> 5, j = (e & 31) << 2;
      *(float4*)&xs[c * 128 + j] = *(const float4*)&Xn[(size_t)(c0 + c) * NP + p0 + j];
    }
    for (int e = threadIdx.x; e < 512; e += 256) {
      int c = e >> 4, j = (e & 15) << 2;
      *(float4*)&wsm[c * 64 + j] = *(const float4*)&gwT[(size_t)(c0 + c) * CO + o0 + j];
    }
    __syncthreads();
#pragma unroll 8
    for (int c = 0; c < 32; c++) {
      float4 w4 = *(const float4*)&wsm[c * 64 + og * 4];
      float4 xa = *(const float4*)&xs[c * 128 + pg * 8];
      float4 xb2 = *(const float4*)&xs[c * 128 + pg * 8 + 4];
      float wr[4] = {w4.x, w4.y, w4.z, w4.w};
      float xr[8] = {xa.x, xa.y, xa.z, xa.w, xb2.x, xb2.y, xb2.z, xb2.w};
#pragma unroll
      for (int j = 0; j < 4; j++)
#pragma unroll
        for (int q = 0; q < 8; q++) acc[j][q] = fmaf(wr[j], xr[q], acc[j][q]);
    }
  }
  float* Un = Uo + (size_t)n * CO * NP;
#pragma unroll
  for (int j = 0; j < 4; j++) {
    *(float4*)&Un[(size_t)(o + j) * NP + p] =
        make_float4(acc[j][0], acc[j][1], acc[j][2], acc[j][3]);
    *(float4*)&Un[(size_t)(o + j) * NP + p + 4] =
        make_float4(acc[j][4], acc[j][5], acc[j][6], acc[j][7]);
  }
}

// Fused: residual 1x1 (strided) + [A-mix + BN1 + ReLU -> g] + 9-tap temporal conv
// (bn2 prescaled into twT, beta holds s2*tb+b2+rb) + final ReLU.
// U:(nc,CO,18,Tin) pre-A-mix; Xin:(nc,CIN,18,Tin); Out:(nc,CO,18,Tout)
template <int CIN, int CO, int S>
__global__ __launch_bounds__(256, 2) void k_tcn(
    const float* __restrict__ U, const float* __restrict__ Xin,
    const float* __restrict__ Amat, const float* __restrict__ gb,
    const float* __restrict__ bn1g, const float* __restrict__ bn1b,
    const float* __restrict__ twT, const float* __restrict__ rwT,
    const float* __restrict__ beta, float* __restrict__ Out, int Tin, int Tout) {
  constexpr int TT = 16;
  constexpr int SPAN = (TT - 1) * S + 9;  // 24 (S=1) or 39 (S=2)
  constexpr int USZ = (4 * SPAN * 20 > 2304) ? 4 * SPAN * 20 : 2304;
  const int n = blockIdx.x;
  const int to0 = blockIdx.y * TT;
  const int o0 = blockIdx.z * 64;
  const int og = threadIdx.x & 15;
  const int tol = threadIdx.x >> 4;
  const int o = o0 + og * 4;

  __shared__ __align__(16) float g_lds[4 * SPAN * 20];
  __shared__ __align__(16) float u_lds[USZ];
  __shared__ __align__(16) float w_lds[4 * 9 * 64];
  __shared__ __align__(16) float A_lds[18 * 20];

  for (int e = threadIdx.x; e < 324; e += 256)
    A_lds[(e / 18) * 20 + (e % 18)] = Amat[e];

  float acc[4][18];
#pragma unroll
  for (int j = 0; j < 4; j++) {
    float b = beta[o + j];
#pragma unroll
    for (int v = 0; v < 18; v++) acc[j][v] = b;
  }

  // ---- residual: acc += rw^T * Xin[:, :, S*to] ----
  const int tr0 = S * to0;
  for (int c0 = 0; c0 < CIN; c0 += 8) {
    const int cc = (CIN - c0 < 8) ? (CIN - c0) : 8;
    __syncthreads();
    for (int e = threadIdx.x; e < cc * 288; e += 256) {
      int ci = e / 288, r = e % 288;
      int v = r >> 4, tl = r & 15;
      u_lds[e] = Xin[((size_t)(n * CIN + c0 + ci) * 18 + v) * Tin + tr0 + S * tl];
    }
    for (int e = threadIdx.x; e < cc * 64; e += 256)
      w_lds[e] = rwT[(size_t)(c0 + (e >> 6)) * CO + o0 + (e & 63)];
    __syncthreads();
    for (int ci = 0; ci < cc; ci++) {
      float4 w4 = *(const float4*)&w_lds[ci * 64 + og * 4];
#pragma unroll
      for (int v = 0; v < 18; v++) {
        float xv = u_lds[ci * 288 + v * 16 + tol];
        acc[0][v] = fmaf(w4.x, xv, acc[0][v]);
        acc[1][v] = fmaf(w4.y, xv, acc[1][v]);
        acc[2][v] = fmaf(w4.z, xv, acc[2][v]);
        acc[3][v] = fmaf(w4.w, xv, acc[3][v]);
      }
    }
  }

  // ---- temporal conv over on-the-fly g ----
  const int tib = S * to0 - 4;
  const float rs = 1.0f / sqrtf(1.0f + EPS);
  for (int c0 = 0; c0 < CO; c0 += 4) {
    __syncthreads();
    // stage U chunk [4][SPAN][20] (zero outside [0,Tin))
    for (int e = threadIdx.x; e < 4 * 18 * SPAN; e += 256) {
      int c = e / (18 * SPAN), r = e % (18 * SPAN);
      int v = r / SPAN, ti = r % SPAN;
      int tg = tib + ti;
      float val = 0.0f;
      if (tg >= 0 && tg < Tin)
        val = U[((size_t)(n * CO + c0 + c) * 18 + v) * Tin + tg];
      u_lds[(c * SPAN + ti) * 20 + v] = val;
    }
    // stage prescaled weights [4][9][64]
    for (int e = threadIdx.x; e < 4 * 9 * 16; e += 256) {
      int row = e >> 4;
      int j = (e & 15) << 2;
      *(float4*)&w_lds[row * 64 + j] = *(const float4*)&twT[(size_t)(c0 * 9 + row) * CO + o0 + j];
    }
    __syncthreads();
    // phase2: g = relu(bn1(A-mix(U) + gb)); zero-pad outside time range
    for (int e = threadIdx.x; e < 4 * SPAN; e += 256) {
      int c = e / SPAN, ti = e % SPAN;
      int tg = tib + ti;
      float* gr = &g_lds[(c * SPAN + ti) * 20];
      if (tg >= 0 && tg < Tin) {
        const float* ur = &u_lds[(c * SPAN + ti) * 20];
        const float4 ua = *(const float4*)&ur[0];
        const float4 ub = *(const float4*)&ur[4];
        const float4 uc = *(const float4*)&ur[8];
        const float4 ud = *(const float4*)&ur[12];
        const float ue = ur[16], uf = ur[17];
        float s1 = bn1g[c0 + c] * rs, b1v = bn1b[c0 + c], g0v = gb[c0 + c];
#pragma unroll
        for (int v = 0; v < 18; v++) {
          const float* ar = &A_lds[v * 20];
          float4 a0 = *(const float4*)&ar[0];
          float4 a1 = *(const float4*)&ar[4];
          float4 a2 = *(const float4*)&ar[8];
          float4 a3 = *(const float4*)&ar[12];
          float z = g0v;
          z = fmaf(a0.x, ua.x, z); z = fmaf(a0.y, ua.y, z);
          z = fmaf(a0.z, ua.z, z); z = fmaf(a0.w, ua.w, z);
          z = fmaf(a1.x, ub.x, z); z = fmaf(a1.y, ub.y, z);
          z = fmaf(a1.z, ub.z, z); z = fmaf(a1.w, ub.w, z);
          z = fmaf(a2.x, uc.x, z); z = fmaf(a2.y, uc.y, z);
          z = fmaf(a2.z, uc.z, z); z = fmaf(a2.w, uc.w, z);
          z = fmaf(a3.x, ud.x, z); z = fmaf(a3.y, ud.y, z);
          z = fmaf(a3.z, ud.z, z); z = fmaf(a3.w, ud.w, z);
          z = fmaf(ar[16], ue, z); z = fmaf(ar[17], uf, z);
          z = fmaf(z, s1, b1v);
          gr[v] = z > 0.0f ? z : 0.0f;
        }
      } else {
#pragma unroll
        for (int v = 0; v < 18; v++) gr[v] = 0.0f;
      }
    }
    __syncthreads();
    // phase3: acc[o][v] += sum_{c,k} twT[c,k,o] * g[c, S*tol+k, v]
    for (int c = 0; c < 4; c++) {
#pragma unroll
      for (int k = 0; k < 9; k++) {
        const float4 w4 = *(const float4*)&w_lds[(c * 9 + k) * 64 + og * 4];
        const float* gr = &g_lds[(c * SPAN + S * tol + k) * 20];
        const float4 ga = *(const float4*)&gr[0];
        const float4 gbv = *(const float4*)&gr[4];
        const float4 gc = *(const float4*)&gr[8];
        const float4 gd = *(const float4*)&gr[12];
        float gv[18] = {ga.x, ga.y, ga.z, ga.w, gbv.x, gbv.y, gbv.z, gbv.w,
                        gc.x, gc.y, gc.z, gc.w, gd.x, gd.y, gd.z, gd.w,
                        gr[16], gr[17]};
#pragma unroll
        for (int v = 0; v < 18; v++) {
          acc[0][v] = fmaf(w4.x, gv[v], acc[0][v]);
          acc[1][v] = fmaf(w4.y, gv[v], acc[1][v]);
          acc[2][v] = fmaf(w4.z, gv[v], acc[2][v]);
          acc[3][v] = fmaf(w4.w, gv[v], acc[3][v]);
        }
      }
    }
  }
#pragma unroll
  for (int j = 0; j < 4; j++)
#pragma unroll
    for (int v = 0; v < 18; v++) {
      float r = acc[j][v];
      Out[((size_t)(n * CO + o + j) * 18 + v) * Tout + to0 + tol] = r > 0.0f ? r : 0.0f;
    }
}

// in-place EMA over time; 64 rows per block, 1 wave; rows contiguous length T
__global__ __launch_bounds__(64) void k_smooth(float* __restrict__ X, int T) {
  __shared__ float tile[64 * 33];  // 8.4 KB; stride 33 -> 2-way bank alias (free)
  size_t r0 = (size_t)blockIdx.x * 64;
  float s = 0.0f;
  for (int tc = 0; tc < T; tc += 32) {
    for (int e = threadIdx.x; e < 64 * 32; e += 64) {
      int r = e >> 5, tt = e & 31;
      tile[r * 33 + tt] = X[(r0 + r) * T + tc + tt];
    }
    __syncthreads();
    float* row = &tile[threadIdx.x * 33];
    int start = 0;
    if (tc == 0) { s = row[0]; start = 1; }
    for (int tt = start; tt < 32; tt++) {
      s = fmaf(0.85f, s, 0.15f * row[tt]);
      row[tt] = s;
    }
    __syncthreads();
    for (int e = threadIdx.x; e < 64 * 32; e += 64) {
      int r = e >> 5, tt = e & 31;
      X[(r0 + r) * T + tc + tt] = tile[r * 33 + tt];
    }
    __syncthreads();
  }
}

// mean over (v,t)=1152 then 10-way FC.  H:(nc,256,18,64)
__global__ __launch_bounds__(256, 4) void k_poolfc(
    const float* __restrict__ H, const float* __restrict__ fcw,
    const float* __restrict__ fcb, float* __restrict__ out) {
  int n = blockIdx.x;
  __shared__ float pool[256];
  const float* row = H + (size_t)(n * 256 + threadIdx.x) * 1152;
  float s = 0.0f;
  for (int i = 0; i < 1152; i += 4) {
    float4 x4 = *(const float4*)&row[i];
    s += x4.x + x4.y + x4.z + x4.w;
  }
  pool[threadIdx.x] = s * (1.0f / 1152.0f);
  __syncthreads();
  if (threadIdx.x < 10) {
    float a = fcb[threadIdx.x];
    for (int c = 0; c < 256; c++) a = fmaf(fcw[threadIdx.x * 256 + c], pool[c], a);
    out[n * 10 + threadIdx.x] = a;
  }
}

extern "C" void kernel_launch(void* const* d_in, const int* in_sizes, int n_in,
                              void* d_out, int out_size, void* d_ws, size_t ws_size,
                              hipStream_t stream) {
  const float* x    = (const float*)d_in[0];
  const float* Amat = (const float*)d_in[1];
  const float* dbng = (const float*)d_in[2];
  const float* dbnb = (const float*)d_in[3];
  const float* gw1 = (const float*)d_in[4];   const float* gb1 = (const float*)d_in[5];
  const float* bn1g1 = (const float*)d_in[6]; const float* bn1b1 = (const float*)d_in[7];
  const float* tw1 = (const float*)d_in[8];   const float* tb1 = (const float*)d_in[9];
  const float* bn2g1 = (const float*)d_in[10]; const float* bn2b1 = (const float*)d_in[11];
  const float* rw1 = (const float*)d_in[12];  const float* rb1 = (const float*)d_in[13];
  const float* gw2 = (const float*)d_in[14];  const float* gb2 = (const float*)d_in[15];
  const float* bn1g2 = (const float*)d_in[16]; const float* bn1b2 = (const float*)d_in[17];
  const float* tw2 = (const float*)d_in[18];  const float* tb2 = (const float*)d_in[19];
  const float* bn2g2 = (const float*)d_in[20]; const float* bn2b2 = (const float*)d_in[21];
  const float* rw2 = (const float*)d_in[22];  const float* rb2 = (const float*)d_in[23];
  const float* gw3 = (const float*)d_in[24];  const float* gb3 = (const float*)d_in[25];
  const float* bn1g3 = (const float*)d_in[26]; const float* bn1b3 = (const float*)d_in[27];
  const float* tw3 = (const float*)d_in[28];  const float* tb3 = (const float*)d_in[29];
  const float* bn2g3 = (const float*)d_in[30]; const float* bn2b3 = (const float*)d_in[31];
  const float* rw3 = (const float*)d_in[32];  const float* rb3 = (const float*)d_in[33];
  const float* fcw = (const float*)d_in[34];  const float* fcb = (const float*)d_in[35];
  (void)in_sizes; (void)n_in; (void)out_size;

  // ---- weights region at ws base (fixed, NC-independent) ----
  float* f = (float*)d_ws;
  float* gwT2 = f;                   // 8192
  float* gwT3 = gwT2 + 8192;         // 32768
  float* rwT1 = gwT3 + 32768;        // 128
  float* rwT2 = rwT1 + 128;          // 8192
  float* rwT3 = rwT2 + 8192;         // 32768
  float* twT1 = rwT3 + 32768;        // 36864
  float* twT2 = twT1 + 36864;        // 147456
  float* twT3 = twT2 + 147456;       // 589824
  float* beta1 = twT3 + 589824;      // 64
  float* beta2 = beta1 + 64;         // 128
  float* beta3 = beta2 + 128;        // 256
  const size_t WOFF = 856832;        // weights end, aligned up to 256 floats

  // ---- pick largest chunk NC that fits ws_size ----
  int NC = 32;
  while (NC > 1 && (WOFF + (size_t)NC * 1188864ULL) * 4ULL > ws_size) NC >>= 1;
  float* Us = f + WOFF;                        // NC*589824
  float* B1 = Us + (size_t)NC * 589824;        // NC*294912
  float* B2 = B1 + (size_t)NC * 294912;        // NC*294912
  float* XB = B2 + (size_t)NC * 294912;        // NC*9216

  // ---- weight prep (idempotent, tiny) ----
  k_transpose<<<32, 256, 0, stream>>>(gw2, gwT2, 128, 64);
  k_transpose<<<128, 256, 0, stream>>>(gw3, gwT3, 256, 128);
  k_transpose<<<1, 256, 0, stream>>>(rw1, rwT1, 64, 2);
  k_transpose<<<32, 256, 0, stream>>>(rw2, rwT2, 128, 64);
  k_transpose<<<128, 256, 0, stream>>>(rw3, rwT3, 256, 128);
  k_prep_tw<<<144, 256, 0, stream>>>(tw1, bn2g1, twT1, 64);
  k_prep_tw<<<576, 256, 0, stream>>>(tw2, bn2g2, twT2, 128);
  k_prep_tw<<<2304, 256, 0, stream>>>(tw3, bn2g3, twT3, 256);
  k_beta<<<1, 256, 0, stream>>>(bn2g1, bn2b1, tb1, rb1, beta1, 64);
  k_beta<<<1, 256, 0, stream>>>(bn2g2, bn2b2, tb2, rb2, beta2, 128);
  k_beta<<<1, 256, 0, stream>>>(bn2g3, bn2b3, tb3, rb3, beta3, 256);

  // ---- whole network per N-chunk ----
  for (int n0 = 0; n0 < 128; n0 += NC) {
    // block 1
    k_front1<<<dim3(NC, 4), 256, 0, stream>>>(
        x + (size_t)n0 * 9216, dbng, dbnb, gw1, Us, XB);
    k_tcn<2, 64, 1><<<dim3(NC, 16, 1), 256, 0, stream>>>(
        Us, XB, Amat, gb1, bn1g1, bn1b1, twT1, rwT1, beta1, B1, 256, 256);
    k_smooth<<<NC * 18, 64, 0, stream>>>(B1, 256);
    // block 2
    k_ugemm<64, 128><<<dim3(NC, 36, 2), 256, 0, stream>>>(B1, gwT2, Us, 4608);
    k_tcn<64, 128, 2><<<dim3(NC, 8, 2), 256, 0, stream>>>(
        Us, B1, Amat, gb2, bn1g2, bn1b2, twT2, rwT2, beta2, B2, 256, 128);
    k_smooth<<<NC * 36, 64, 0, stream>>>(B2, 128);
    // block 3 (output reuses B1 -- dead after tcn2)
    k_ugemm<128, 256><<<dim3(NC, 18, 4), 256, 0, stream>>>(B2, gwT3, Us, 2304);
    k_tcn<128, 256, 2><<<dim3(NC, 4, 4), 256, 0, stream>>>(
        Us, B2, Amat, gb3, bn1g3, bn1b3, twT3, rwT3, beta3, B1, 128, 64);
    k_smooth<<<NC * 72, 64, 0, stream>>>(B1, 64);
    // head
    k_poolfc<<<NC, 256, 0, stream>>>(B1, fcw, fcb, (float*)d_out + (size_t)n0 * 10);
  }
}